// Round 5
// baseline (85.068 us; speedup 1.0000x reference)
//
#include <hip/hip_runtime.h>

typedef _Float16 f16;
typedef _Float16 f16x2 __attribute__((ext_vector_type(2)));
typedef _Float16 f16x4v __attribute__((ext_vector_type(4)));
typedef _Float16 f16x8 __attribute__((ext_vector_type(8)));
typedef float f32x4 __attribute__((ext_vector_type(4)));
typedef float f32x16 __attribute__((ext_vector_type(16)));
typedef unsigned int u32x4 __attribute__((ext_vector_type(4)));

#define LOG2E 1.44269504088896f
#define MFMA32(a, b, c) __builtin_amdgcn_mfma_f32_32x32x16_f16(a, b, c, 0, 0, 0)

typedef __attribute__((address_space(1))) const unsigned int* gas_t;
typedef __attribute__((address_space(3))) unsigned int* las_t;

// async global->LDS, 16B per lane: LDS dest = base + lane*16 (wave-uniform base)
static __device__ inline void gload16(const void* g, void* l) {
    __builtin_amdgcn_global_load_lds((gas_t)g, (las_t)l, 16, 0, 0);
}

static __device__ inline f16x8 f16x8_zero() {
    f16x8 v;
#pragma unroll
    for (int i = 0; i < 8; ++i) v[i] = (f16)0.f;
    return v;
}

// v_permlane32_swap_b32: a' = [a.row0 | b.row0], b' = [a.row1 | b.row1]
static __device__ inline void perm32swap(unsigned int& a, unsigned int& b) {
    asm("v_permlane32_swap_b32 %0, %1" : "+v"(a), "+v"(b));
}

// ---------------- Kernel 1: projections ----------------
// Outputs: fO/gO [B*4096][8] f16 (g pre-scaled by log2e), and h in 32x32x16
// FRAGMENT-MAJOR layout: per 16-key group (1024 f16): [cb][nhalf][c&31][n&7];
// a PV A-fragment (16 keys, 32 ch) is one lane-contiguous 1KB block.
__global__ __launch_bounds__(256) void proj_kernel(
    const float* __restrict__ x, const float* __restrict__ Kf,
    const float* __restrict__ Kg, const float* __restrict__ Kh,
    const float* __restrict__ bf, const float* __restrict__ bg,
    const float* __restrict__ bh,
    f16* __restrict__ fO, f16* __restrict__ gO, f16* __restrict__ hF)
{
    __shared__ float KT[80 * 64];   // KT[c][d]: c<8 -> f, 8..15 -> g (scaled), 16..79 -> h
    __shared__ float bias[80];
    const int tid = threadIdx.x;

    for (int i = tid; i < 512; i += 256) {          // Kf/Kg are [64][8]
        int d = i >> 3, j = i & 7;
        KT[j * 64 + d] = Kf[i];
        KT[(8 + j) * 64 + d] = Kg[i] * LOG2E;
    }
    for (int i = tid; i < 4096; i += 256) {         // Kh is [64][64]
        int d = i >> 6, c = i & 63;
        KT[(16 + c) * 64 + d] = Kh[i];
    }
    if (tid < 8) { bias[tid] = bf[tid]; bias[8 + tid] = bg[tid] * LOG2E; }
    if (tid >= 16 && tid < 80) bias[tid] = bh[tid - 16];
    __syncthreads();

    const int quarter = tid >> 6;                   // wave id: which 20 output channels
    const int px = blockIdx.x * 64 + (tid & 63);    // pixel (b*4096 + n)
    const float4* xp = (const float4*)(x + (size_t)px * 64);
    float4 xr[16];
#pragma unroll
    for (int i = 0; i < 16; ++i) xr[i] = xp[i];

    float res[20];
    const int c0 = quarter * 20;
#pragma unroll
    for (int cc = 0; cc < 20; ++cc) {
        const int c = c0 + cc;
        float acc = bias[c];
        const float4* wv = (const float4*)(KT + c * 64);
#pragma unroll
        for (int i = 0; i < 16; ++i) {
            float4 w = wv[i];
            acc = fmaf(xr[i].x, w.x, acc);
            acc = fmaf(xr[i].y, w.y, acc);
            acc = fmaf(xr[i].z, w.z, acc);
            acc = fmaf(xr[i].w, w.w, acc);
        }
        res[cc] = acc;
    }

    const int b = px >> 12, n = px & 4095;
    const size_t hbase = (size_t)b * 262144 + (size_t)(n >> 4) * 1024
                       + (size_t)((n >> 3) & 1) * 256 + (n & 7);
    if (quarter == 0) {
        f16x8 fv, gv;
#pragma unroll
        for (int j = 0; j < 8; ++j) { fv[j] = (f16)res[j]; gv[j] = (f16)res[8 + j]; }
        *(f16x8*)(fO + (size_t)px * 8) = fv;
        *(f16x8*)(gO + (size_t)px * 8) = gv;
#pragma unroll
        for (int cc = 16; cc < 20; ++cc) {
            const int hc = c0 + cc - 16;
            hF[hbase + (hc >> 5) * 512 + (hc & 31) * 8] = (f16)res[cc];
        }
    } else {
#pragma unroll
        for (int cc = 0; cc < 20; ++cc) {
            const int hc = c0 + cc - 16;
            hF[hbase + (hc >> 5) * 512 + (hc & 31) * 8] = (f16)res[cc];
        }
    }
}

// ---------------- Kernel 2: flash attention (32x32 MFMA, split-K, LDS-staged) --
// Block = 4 waves x 32 q-rows = 128 q. Per 64-key tile: h (8KB) + f (1KB) staged
// into LDS via global_load_lds (zero VGPR cost), double-buffered, one
// __syncthreads per iter (its vmcnt(0)+lgkmcnt(0)+barrier drain IS the sync).
// Swapped QK^T via mfma_32x32x16_f16; P assembled in-register via
// cvt_pkrtz + permlane32_swap; PV O^T = H^T P^T from LDS fragments. Defer-max.
template<int NSPLIT>
__global__ __launch_bounds__(256, 4) void attn5_kernel(
    const f16* __restrict__ fO, const f16* __restrict__ gO,
    const f16* __restrict__ hF, const float* __restrict__ x,
    const float* __restrict__ gamma, float* __restrict__ out,
    f16* __restrict__ po, float* __restrict__ pml)
{
    __shared__ __align__(16) char lds[2][9216];   // [buf][ h:8192 | f:1024 ]

    const int tid  = threadIdx.x;
    const int w    = tid >> 6;
    const int lane = tid & 63;
    const int q5   = lane & 31;
    const int hi   = lane >> 5;

    const int b = blockIdx.x & 7;
    int kc, qt;
    if (NSPLIT == 4)      { kc = (blockIdx.x >> 3) & 3; qt = blockIdx.x >> 5; }
    else if (NSPLIT == 2) { kc = (blockIdx.x >> 3) & 1; qt = blockIdx.x >> 4; }
    else                  { kc = 0;                     qt = blockIdx.x >> 3; }

    const int KEYS = 4096 / NSPLIT;
    const int NIT  = KEYS / 64;
    const int k0   = kc * KEYS;
    const int qrow = qt * 128 + w * 32 + q5;

    // global tile bases (bytes)
    const char* hTile = (const char*)hF + ((size_t)b * 262144 + (size_t)k0 * 64) * 2;
    const char* fTile = (const char*)fO + ((size_t)b * 32768 + (size_t)k0 * 8) * 2;

    // QK B operand: lanes<32 hold g[q][0..7] (k rows 0..7); lanes>=32 zero (K pad 8->16).
    f16x8 gfrag = f16x8_zero();
    if (lane < 32) gfrag = *(const f16x8*)(gO + (size_t)b * 32768 + (size_t)qrow * 8);

    f32x16 acc0, acc1;
#pragma unroll
    for (int i = 0; i < 16; ++i) { acc0[i] = 0.f; acc1[i] = 0.f; }
    float mrun = -1e30f, lpart = 0.f;

    // ---- stage tile 0 ----
    {
        const char* hg = hTile + w * 2048 + lane * 16;
        char* hl = &lds[0][0] + w * 2048;
        gload16(hg, hl);
        gload16(hg + 1024, hl + 1024);
        if (w == 3) gload16(fTile + lane * 16, &lds[0][8192]);
    }
    __syncthreads();

    for (int t = 0; t < NIT; ++t) {
        const int cur = t & 1;
        if (t + 1 < NIT) {                          // issue next-tile stage (async)
            const char* hg = hTile + (size_t)(t + 1) * 8192 + w * 2048 + lane * 16;
            char* hl = &lds[cur ^ 1][0] + w * 2048;
            gload16(hg, hl);
            gload16(hg + 1024, hl + 1024);
            if (w == 3) gload16(fTile + (size_t)(t + 1) * 1024 + lane * 16, &lds[cur ^ 1][8192]);
        }

        const f16* hl = (const f16*)&lds[cur][0];
        const f16* fl = (const f16*)&lds[cur][8192];

        // ---- QK^T: S^T[key][q], q = lane&31 ----
        const f16x8 fa0 = *(const f16x8*)(fl + q5 * 8);          // keys 0..31
        const f16x8 fa1 = *(const f16x8*)(fl + 256 + q5 * 8);    // keys 32..63
        f32x16 zc;
#pragma unroll
        for (int i = 0; i < 16; ++i) zc[i] = 0.f;
        f32x16 s0 = MFMA32(fa0, gfrag, zc);
        f32x16 s1 = MFMA32(fa1, gfrag, zc);

        // ---- online softmax (log2 units) ----
        f32x16 mt;
#pragma unroll
        for (int i = 0; i < 16; ++i) mt[i] = fmaxf(s0[i], s1[i]);
#pragma unroll
        for (int st = 8; st >= 1; st >>= 1)
#pragma unroll
            for (int i = 0; i < st; ++i) mt[i] = fmaxf(mt[i], mt[i + st]);
        float m8 = fmaxf(mt[0], __shfl_xor(mt[0], 32));

        if (__any(m8 > mrun + 8.f)) {                    // defer-max (T13)
            const float mnew = fmaxf(mrun, m8);
            const float sc = exp2f(mrun - mnew);
            mrun = mnew;
#pragma unroll
            for (int i = 0; i < 16; ++i) { acc0[i] *= sc; acc1[i] *= sc; }
            lpart *= sc;
        }

#pragma unroll
        for (int i = 0; i < 16; ++i) {                   // exp in place
            s0[i] = exp2f(s0[i] - mrun);
            s1[i] = exp2f(s1[i] - mrun);
        }

        // ---- pack to f16 pairs (consecutive regs = consecutive keys) ----
        unsigned int wr[16];
#pragma unroll
        for (int i = 0; i < 8; ++i) {
            wr[i]     = __builtin_bit_cast(unsigned int, __builtin_amdgcn_cvt_pkrtz(s0[2 * i], s0[2 * i + 1]));
            wr[8 + i] = __builtin_bit_cast(unsigned int, __builtin_amdgcn_cvt_pkrtz(s1[2 * i], s1[2 * i + 1]));
        }

        // ---- l partial via v_pk_add_f16 tree over own 32 keys ----
        {
            f16x2 s8[8];
#pragma unroll
            for (int i = 0; i < 8; ++i)
                s8[i] = __builtin_bit_cast(f16x2, wr[i]) + __builtin_bit_cast(f16x2, wr[8 + i]);
#pragma unroll
            for (int st = 4; st >= 1; st >>= 1)
#pragma unroll
                for (int i = 0; i < st; ++i) s8[i] = s8[i] + s8[i + st];
            lpart += (float)s8[0][0] + (float)s8[0][1];
        }

        // ---- assemble PV B-fragments in-register: 8 permlane32_swap ----
        perm32swap(wr[0], wr[2]);   perm32swap(wr[1], wr[3]);    // keys  0..15
        perm32swap(wr[4], wr[6]);   perm32swap(wr[5], wr[7]);    // keys 16..31
        perm32swap(wr[8], wr[10]);  perm32swap(wr[9], wr[11]);   // keys 32..47
        perm32swap(wr[12], wr[14]); perm32swap(wr[13], wr[15]);  // keys 48..63

        // ---- PV: O^T[c][q] += H^T[c][k] P^T[k][q], fragments from LDS ----
#pragma unroll
        for (int kk = 0; kk < 4; ++kk) {
            u32x4 tv;
            tv[0] = wr[kk * 4 + 0]; tv[1] = wr[kk * 4 + 1];
            tv[2] = wr[kk * 4 + 2]; tv[3] = wr[kk * 4 + 3];
            const f16x8 pf = __builtin_bit_cast(f16x8, tv);
            const f16x8 ha0 = *(const f16x8*)(hl + kk * 1024 + lane * 8);
            const f16x8 ha1 = *(const f16x8*)(hl + kk * 1024 + 512 + lane * 8);
            acc0 = MFMA32(ha0, pf, acc0);
            acc1 = MFMA32(ha1, pf, acc1);
        }

        if (t + 1 < NIT) __syncthreads();   // drains vmcnt(0)+lgkmcnt(0): staged tile ready
    }

    lpart += __shfl_xor(lpart, 32);

    if (NSPLIT == 1) {
        const float rin = 1.f / lpart;
        const float gm = gamma[0];
        const size_t qg = (size_t)b * 4096 + qrow;
#pragma unroll
        for (int cb = 0; cb < 2; ++cb)
#pragma unroll
            for (int r = 0; r < 4; ++r) {
                const size_t o = qg * 64 + cb * 32 + r * 8 + hi * 4;
                f32x4 v;
#pragma unroll
                for (int j = 0; j < 4; ++j) {
                    const float a = (cb == 0) ? acc0[4 * r + j] : acc1[4 * r + j];
                    v[j] = fmaf(gm, a * rin, x[o + j]);
                }
                *(f32x4*)(out + o) = v;
            }
    } else {
        f16* pob = po + (size_t)((kc * 8 + b) * 128 + qt * 4 + w) * 2048;
#pragma unroll
        for (int cb = 0; cb < 2; ++cb)
#pragma unroll
            for (int r = 0; r < 4; ++r) {
                uint2 v;
                const float a0 = (cb == 0) ? acc0[4 * r + 0] : acc1[4 * r + 0];
                const float a1 = (cb == 0) ? acc0[4 * r + 1] : acc1[4 * r + 1];
                const float a2 = (cb == 0) ? acc0[4 * r + 2] : acc1[4 * r + 2];
                const float a3 = (cb == 0) ? acc0[4 * r + 3] : acc1[4 * r + 3];
                v.x = __builtin_bit_cast(unsigned int, __builtin_amdgcn_cvt_pkrtz(a0, a1));
                v.y = __builtin_bit_cast(unsigned int, __builtin_amdgcn_cvt_pkrtz(a2, a3));
                *(uint2*)(pob + (cb * 4 + r) * 256 + lane * 4) = v;
            }
        if (lane < 32) {
            float2 ml; ml.x = mrun; ml.y = lpart;
            *(float2*)(pml + ((size_t)(kc * 8 + b) * 4096 + qrow) * 2) = ml;
        }
    }
}

// ---------------- Kernel 3: split-K combine (po in f16) ----------------
template<int NS>
__global__ __launch_bounds__(256) void combine_kernel(
    const f16* __restrict__ po, const float* __restrict__ pml,
    const float* __restrict__ x, const float* __restrict__ gamma,
    float* __restrict__ out)
{
    const int t    = blockIdx.x * 256 + threadIdx.x;    // 524288 threads
    const int lane = t & 63;
    const int r    = (t >> 6) & 3;
    const int cb   = (t >> 8) & 1;
    const int w    = (t >> 9) & 3;
    const int qt   = (t >> 11) & 31;
    const int b    = (t >> 16) & 7;
    const int q    = qt * 128 + w * 32 + (lane & 31);
    const int c    = cb * 32 + r * 8 + (lane >> 5) * 4;

    float m[NS], l[NS];
    float M = -1e30f;
#pragma unroll
    for (int kc = 0; kc < NS; ++kc) {
        const float2 ml = *(const float2*)(pml + ((size_t)(kc * 8 + b) * 4096 + q) * 2);
        m[kc] = ml.x; l[kc] = ml.y;
        M = fmaxf(M, ml.x);
    }
    float denom = 0.f;
    f32x4 num;
#pragma unroll
    for (int j = 0; j < 4; ++j) num[j] = 0.f;
#pragma unroll
    for (int kc = 0; kc < NS; ++kc) {
        const float e = exp2f(m[kc] - M);
        denom = fmaf(e, l[kc], denom);
        const f16x4v v = *(const f16x4v*)(po + (size_t)((kc * 8 + b) * 128 + qt * 4 + w) * 2048
                                             + (cb * 4 + r) * 256 + lane * 4);
#pragma unroll
        for (int j = 0; j < 4; ++j) num[j] = fmaf(e, (float)v[j], num[j]);
    }
    const float sc = gamma[0] / denom;
    const size_t o = ((size_t)b * 4096 + q) * 64 + c;
    const f32x4 xv = *(const f32x4*)(x + o);
    f32x4 ov;
#pragma unroll
    for (int j = 0; j < 4; ++j) ov[j] = fmaf(sc, num[j], xv[j]);
    *(f32x4*)(out + o) = ov;
}

extern "C" void kernel_launch(void* const* d_in, const int* in_sizes, int n_in,
                              void* d_out, int out_size, void* d_ws, size_t ws_size,
                              hipStream_t stream) {
    const float* x     = (const float*)d_in[0];
    const float* Kf    = (const float*)d_in[1];
    const float* Kg    = (const float*)d_in[2];
    const float* Kh    = (const float*)d_in[3];
    const float* bf    = (const float*)d_in[4];
    const float* bg    = (const float*)d_in[5];
    const float* bh    = (const float*)d_in[6];
    const float* gamma = (const float*)d_in[7];
    float* out = (float*)d_out;

    f16* fO = (f16*)d_ws;                               // 512 KB
    f16* gO = (f16*)((char*)d_ws + (512 << 10));        // 512 KB
    f16* hF = (f16*)((char*)d_ws + (1 << 20));          // 4 MB (fragment-major h)
    f16* po = (f16*)((char*)d_ws + (5 << 20));          // NSPLIT*4 MB partial O (f16)

    const size_t need4 = ((size_t)5 << 20) + ((size_t)16 << 20) + ((size_t)1 << 20);
    const size_t need2 = ((size_t)5 << 20) + ((size_t)8 << 20) + ((size_t)1 << 19);

    hipLaunchKernelGGL(proj_kernel, dim3(512), dim3(256), 0, stream,
                       x, Kf, Kg, Kh, bf, bg, bh, fO, gO, hF);
    if (ws_size >= need4) {
        float* pml = (float*)((char*)d_ws + (21u << 20));
        hipLaunchKernelGGL((attn5_kernel<4>), dim3(1024), dim3(256), 0, stream,
                           fO, gO, hF, x, gamma, out, po, pml);
        hipLaunchKernelGGL((combine_kernel<4>), dim3(2048), dim3(256), 0, stream,
                           po, pml, x, gamma, out);
    } else if (ws_size >= need2) {
        float* pml = (float*)((char*)d_ws + (13u << 20));
        hipLaunchKernelGGL((attn5_kernel<2>), dim3(512), dim3(256), 0, stream,
                           fO, gO, hF, x, gamma, out, po, pml);
        hipLaunchKernelGGL((combine_kernel<2>), dim3(2048), dim3(256), 0, stream,
                           po, pml, x, gamma, out);
    } else {
        hipLaunchKernelGGL((attn5_kernel<1>), dim3(256), dim3(256), 0, stream,
                           fO, gO, hF, x, gamma, out, po, (float*)po);
    }
}